// Round 7
// baseline (3525.677 us; speedup 1.0000x reference)
//
#include <hip/hip_runtime.h>
#include <math.h>

#define NPTS  10000
#define KNB   32
#define NCELL 216     // 6*6*6
#define NSGT  157     // ceil(NPTS/64) sort groups

// ---------------------------------------------------------------------------
// helpers
// ---------------------------------------------------------------------------
__device__ __forceinline__ float sgnf(float v) {
    return (v > 0.0f) ? 1.0f : ((v < 0.0f) ? -1.0f : 0.0f);
}

// Open3D ball->cube volume-preserving map, transcribed from the reference.
__device__ __forceinline__ void ball_to_cube(float x, float y, float z,
                                             float& X, float& Y, float& Z) {
    const float EPSF = 1e-12f;
    const float FOPI = (float)(4.0 / 3.14159265358979323846);
    float sq   = x * x + y * y + z * z;
    float norm = sqrtf(fmaxf(sq, EPSF));
    float rho2 = x * x + y * y;
    bool in_cone = (1.25f * z * z > rho2);
    float s1 = sqrtf(3.0f * norm / (norm + fabsf(z)));
    float s2 = norm / sqrtf(fmaxf(rho2, EPSF));
    float s  = in_cone ? s1 : s2;
    float xc = x * s;
    float yc = y * s;
    float zc = in_cone ? sgnf(z) * norm : 1.5f * z;
    if (sq < EPSF) { xc = 0.0f; yc = 0.0f; zc = 0.0f; }
    float sq_xy   = xc * xc + yc * yc;
    float norm_xy = sqrtf(fmaxf(sq_xy, EPSF));
    bool x_major = (fabsf(yc) <= fabsf(xc));
    float xd = (fabsf(xc) < EPSF) ? 1.0f : xc;
    float yd = (fabsf(yc) < EPSF) ? 1.0f : yc;
    float tx = sgnf(xc) * norm_xy;
    float ty = sgnf(yc) * norm_xy;
    float xq = x_major ? tx : ty * FOPI * atanf(xc / yd);
    float yq = x_major ? tx * FOPI * atanf(yc / xd) : ty;
    if (sq_xy < EPSF) { xq = 0.0f; yq = 0.0f; }
    X = xq; Y = yq; Z = zc;
}

// ---------------------------------------------------------------------------
// Kernel 1: per-(point,neighbor) geometry record + neighbor counts.
// Record (uint4): x,y,z = trilinear fracs (fp32 bits); w = packed:
//   [7:0]=c000 cell, [8]=dx?, [9]=dy?, [10]=dz?, [11]=valid, [25:12]=nidx
// ---------------------------------------------------------------------------
__global__ __launch_bounds__(256) void geom_kernel(
    const float* __restrict__ pos, const int* __restrict__ nidx,
    uint4* __restrict__ geo, float* __restrict__ cnt) {
    int t = blockIdx.x * 256 + threadIdx.x;
    if (t >= NPTS * KNB) return;
    int j = t >> 5;
    int k = t & 31;
    int nid = nidx[t];
    float px = pos[j * 3], py = pos[j * 3 + 1], pz = pos[j * 3 + 2];
    float qx = pos[nid * 3], qy = pos[nid * 3 + 1], qz = pos[nid * 3 + 2];
    // exact fp32 (no FMA contraction) to reproduce numpy's mask bit-for-bit
    float dx = __fsub_rn(px, qx), dy = __fsub_rn(py, qy), dz = __fsub_rn(pz, qz);
    float d2 = __fadd_rn(__fadd_rn(__fmul_rn(dx, dx), __fmul_rn(dy, dy)),
                         __fmul_rn(dz, dz));
    bool valid = (d2 <= 2.25f);
    if (valid && nid == 0) {
        for (int kk = 0; kk < k; ++kk) {
            if (nidx[j * KNB + kk] == 0) { valid = false; break; }
        }
    }
    uint4 g = make_uint4(0u, 0u, 0u, 0u);
    if (valid) {
        const float C = (float)(2.0 / 3.0);   // 2/EXTENT
        float ux = (qx - px) * C, uy = (qy - py) * C, uz = (qz - pz) * C;
        float X, Y, Z;
        ball_to_cube(ux, uy, uz, X, Y, Z);
        float cs[3] = { (X + 1.0f) * 2.5f, (Y + 1.0f) * 2.5f, (Z + 1.0f) * 2.5f };
        int i0[3], i1[3];
        float fr[3];
        #pragma unroll
        for (int d = 0; d < 3; ++d) {
            float f0 = floorf(cs[d]);
            fr[d] = cs[d] - f0;               // frac from UNCLIPPED floor (ref)
            int a = (int)f0;
            a = min(max(a, 0), 5);
            i0[d] = a;
            i1[d] = min(a + 1, 5);
        }
        int c000 = (i0[0] * 6 + i0[1]) * 6 + i0[2];
        unsigned bits = (unsigned)c000
                      | ((unsigned)(i1[0] - i0[0]) << 8)
                      | ((unsigned)(i1[1] - i0[1]) << 9)
                      | ((unsigned)(i1[2] - i0[2]) << 10)
                      | (1u << 11)
                      | ((unsigned)nid << 12);
        g.x = __float_as_uint(fr[0]);
        g.y = __float_as_uint(fr[1]);
        g.z = __float_as_uint(fr[2]);
        g.w = bits;
        atomicAdd(&cnt[j], 1.0f);
    }
    geo[t] = g;
}

// ---------------------------------------------------------------------------
// Kernel 2: counting sort of corner contributions by CELL per 64-pt sort
// group. Payload packs nid | ptl<<14 | cell<<20. starts[sg][217] = per-cell
// prefix. Built once, consumed by all 3 conv layers.
// ---------------------------------------------------------------------------
__global__ __launch_bounds__(256) void sort_kernel(
    const uint4* __restrict__ geo, uint2* __restrict__ contribs,
    int* __restrict__ starts) {
    __shared__ int hist[NCELL];
    __shared__ int pref[NCELL + 1];
    const int sg = blockIdx.x, tid = threadIdx.x;
    if (tid < NCELL) hist[tid] = 0;
    __syncthreads();
    const int npts = min(64, NPTS - sg * 64);
    const int nrec = npts * KNB;
    const uint4* gb = geo + (size_t)sg * 64 * KNB;
    for (int r = tid; r < nrec; r += 256) {
        uint4 g = gb[r];
        if (g.w & 2048u) {
            int c000 = g.w & 255u;
            int dxo = (g.w & 256u)  ? 36 : 0;
            int dyo = (g.w & 512u)  ? 6  : 0;
            int dzo = (g.w & 1024u) ? 1  : 0;
            #pragma unroll
            for (int c = 0; c < 8; ++c) {
                int cell = c000 + ((c & 4) ? dxo : 0) + ((c & 2) ? dyo : 0)
                                + ((c & 1) ? dzo : 0);
                atomicAdd(&hist[cell], 1);
            }
        }
    }
    __syncthreads();
    if (tid == 0) {
        int run = 0;
        for (int m = 0; m < NCELL; ++m) { pref[m] = run; run += hist[m]; }
        pref[NCELL] = run;
    }
    __syncthreads();
    for (int i = tid; i < NCELL + 1; i += 256)
        starts[sg * (NCELL + 1) + i] = pref[i];
    if (tid < NCELL) hist[tid] = pref[tid];   // cursors
    __syncthreads();
    uint2* cb = contribs + (size_t)sg * 16384;
    for (int r = tid; r < nrec; r += 256) {
        uint4 g = gb[r];
        if (g.w & 2048u) {
            int ptl = r >> 5;
            float fx = __uint_as_float(g.x);
            float fy = __uint_as_float(g.y);
            float fz = __uint_as_float(g.z);
            int c000 = g.w & 255u;
            int dxo = (g.w & 256u)  ? 36 : 0;
            int dyo = (g.w & 512u)  ? 6  : 0;
            int dzo = (g.w & 1024u) ? 1  : 0;
            int nid = (g.w >> 12) & 16383u;
            #pragma unroll
            for (int c = 0; c < 8; ++c) {
                float wgt = ((c & 4) ? fx : 1.f - fx)
                          * ((c & 2) ? fy : 1.f - fy)
                          * ((c & 1) ? fz : 1.f - fz);
                int cell = c000 + ((c & 4) ? dxo : 0) + ((c & 2) ? dyo : 0)
                                + ((c & 1) ? dzo : 0);
                int p = atomicAdd(&hist[cell], 1);
                cb[p] = make_uint2(__float_as_uint(wgt),
                                   (unsigned)nid | ((unsigned)ptl << 14)
                                                 | ((unsigned)cell << 20));
            }
        }
    }
}

// ---------------------------------------------------------------------------
// Kernel 3: barrier-free record-streaming gather conv.
//   Block = (sort group, K-split segment of cells), 512 threads = 8 waves.
//   Each wave independently owns cells cell0+wv, +8, ... and streams their
//   sorted record runs; NO barriers in the main loop.
//   lane = cout (COUT=32: co=lane&31, ci-range split across halves, both
//   halves same-address atomic-add -> HW-serialized 2-way, no shuffle).
//   Per cell: W block in registers Wreg[CIW] (coalesced loads, amortized
//   over the run). Per record (wave-uniform via __shfl of a lane-cached
//   64-record window): 1 coalesced feats-row load -> per-wave 4-slot LDS
//   ring -> CIW/4 wave-uniform ds_read_b128 (broadcast) + CIW FMAs ->
//   1 conflict-free LDS atomic into out[ptl][co]. 2-record-ahead pipeline
//   hides the feats L2 latency under the previous record's FMA block.
//   Epilogue: one barrier, write out tile to partial (combine handles
//   cnt/bias/relu).
// ---------------------------------------------------------------------------
template<int CIN, int COUT, int KSPLIT>
__global__ __launch_bounds__(512, 2) void conv_kernel(
    const float* __restrict__ feats, const float* __restrict__ W,
    const uint2* __restrict__ contribs, const int* __restrict__ starts,
    float* __restrict__ partial) {
    constexpr int CIW = (COUT == 64) ? CIN : CIN / 2;  // ci's per lane

    __shared__ float out_lds[64 * COUT];
    __shared__ alignas(16) float f_lds[8][4][CIN];     // per-wave 4-slot ring

    const int tid  = threadIdx.x;
    const int lane = tid & 63;
    const int wv   = tid >> 6;
    const int bx   = blockIdx.x;           // sort group
    const int ks   = blockIdx.y;
    const int co     = (COUT == 64) ? lane : (lane & (COUT - 1));
    const int cibase = (COUT == 64) ? 0 : (lane >> 5) * CIW;

    const uint2* cbs = contribs + (size_t)bx * 16384;
    const int*   st  = starts + bx * (NCELL + 1);

    const int cell0 = NCELL * ks / KSPLIT;
    const int cell1 = NCELL * (ks + 1) / KSPLIT;

    for (int i = tid; i < 64 * COUT; i += 512) out_lds[i] = 0.f;
    __syncthreads();

    auto bcast = [&](uint2 v, int r) -> uint2 {
        uint2 o;
        o.x = (unsigned)__shfl((int)v.x, r);
        o.y = (unsigned)__shfl((int)v.y, r);
        return o;
    };
    auto ldf = [&](uint2 rc) -> float {
        return (lane < CIN)
            ? feats[(size_t)(rc.y & 16383u) * CIN + lane] : 0.f;
    };

    float Wreg[CIW];

    for (int cell = cell0 + wv; cell < cell1; cell += 8) {
        const int s = st[cell], e = st[cell + 1];
        if (s == e) continue;
        // stage this cell's W block into registers (coalesced over lanes)
        #pragma unroll
        for (int i = 0; i < CIW; ++i)
            Wreg[i] = W[((size_t)cell * CIN + cibase + i) * COUT + co];

        for (int cs = s; cs < e; cs += 64) {
            const int n = min(64, e - cs);
            uint2 vrec = make_uint2(0u, 0u);
            if (cs + lane < e) vrec = cbs[cs + lane];

            // prologue: rcA/fA = record 0 (written to slot 0), rcB/fB = rec 1
            uint2 rcA = bcast(vrec, 0);
            float fA = ldf(rcA);
            if (lane < CIN) f_lds[wv][0][lane] = fA;
            uint2 rcB = rcA; float fB = 0.f;
            if (n > 1) { rcB = bcast(vrec, 1); fB = ldf(rcB); }

            for (int r = 0; r < n; ++r) {
                // issue load for record r+2
                uint2 rcC = rcB; float fC = 0.f;
                if (r + 2 < n) { rcC = bcast(vrec, r + 2); fC = ldf(rcC); }
                // write record r+1's row to its slot (load issued last iter)
                if (r + 1 < n && lane < CIN)
                    f_lds[wv][(r + 1) & 3][lane] = fB;
                // FMA over record r from slot r&3 (written >=1 iter ago)
                const float* fp = &f_lds[wv][r & 3][cibase];
                float d0 = 0.f, d1 = 0.f, d2 = 0.f, d3 = 0.f;
                #pragma unroll
                for (int q = 0; q < CIW / 4; ++q) {
                    float4 f4 = *reinterpret_cast<const float4*>(fp + q * 4);
                    d0 = fmaf(f4.x, Wreg[q * 4 + 0], d0);
                    d1 = fmaf(f4.y, Wreg[q * 4 + 1], d1);
                    d2 = fmaf(f4.z, Wreg[q * 4 + 2], d2);
                    d3 = fmaf(f4.w, Wreg[q * 4 + 3], d3);
                }
                float val = __uint_as_float(rcA.x) * ((d0 + d1) + (d2 + d3));
                int ptl = (rcA.y >> 14) & 63;
                atomicAdd(&out_lds[ptl * COUT + co], val);
                rcA = rcB; rcB = rcC; fB = fC;
            }
        }
    }

    __syncthreads();
    for (int i = tid; i < 64 * COUT; i += 512) {
        int ptl = i / COUT, c = i % COUT;
        int nn = bx * 64 + ptl;
        if (nn < NPTS)
            partial[((size_t)ks * NPTS + nn) * COUT + c] = out_lds[i];
    }
}

// ---------------------------------------------------------------------------
// Kernel 4: combine K-split partials, normalize by neighbor count, bias, relu.
// ---------------------------------------------------------------------------
template<int COUT, int KSPLIT>
__global__ __launch_bounds__(256) void combine_kernel(
    const float* __restrict__ partial, const float* __restrict__ cnt,
    const float* __restrict__ bias, float* __restrict__ out) {
    int idx = blockIdx.x * 256 + threadIdx.x;
    if (idx >= NPTS * COUT) return;
    int n = idx / COUT, co = idx % COUT;
    float s = 0.f;
    #pragma unroll
    for (int k2 = 0; k2 < KSPLIT; ++k2)
        s += partial[((size_t)k2 * NPTS + n) * COUT + co];
    float c = cnt[n];
    if (c > 0.f) s /= fmaxf(c, 1.f);
    out[idx] = fmaxf(s + bias[co], 0.f);
}

// ---------------------------------------------------------------------------
// Kernel 5: fused FC chain. One wave per point, __shfl broadcasts.
// ---------------------------------------------------------------------------
__global__ __launch_bounds__(64) void fc_kernel(
    const float* __restrict__ x,
    const float* __restrict__ W1, const float* __restrict__ b1,
    const float* __restrict__ W2, const float* __restrict__ b2,
    const float* __restrict__ W3, const float* __restrict__ b3,
    const float* __restrict__ W4, const float* __restrict__ b4,
    float* __restrict__ out) {
    int n = blockIdx.x;
    int lane = threadIdx.x;
    float xv = (lane < 32) ? x[(size_t)n * 32 + lane] : 0.0f;

    float t = b1[lane];
    for (int ci = 0; ci < 32; ++ci)
        t = fmaf(__shfl(xv, ci), W1[ci * 64 + lane], t);
    float h1 = fmaxf(t, 0.0f);

    t = b2[lane];
    for (int ci = 0; ci < 64; ++ci)
        t = fmaf(__shfl(h1, ci), W2[ci * 64 + lane], t);
    float h2 = fmaxf(t, 0.0f);

    int l32 = lane & 31;
    t = b3[l32];
    for (int ci = 0; ci < 64; ++ci)
        t = fmaf(__shfl(h2, ci), W3[ci * 32 + l32], t);
    float h3 = fmaxf(t, 0.0f);

    int ch = (lane < 3) ? lane : 0;
    float o = b4[ch];
    for (int ci = 0; ci < 32; ++ci)
        o = fmaf(__shfl(h3, ci), W4[ci * 3 + ch], o);
    if (lane < 3) out[(size_t)n * 3 + lane] = o;
}

// ---------------------------------------------------------------------------
// launch
// ---------------------------------------------------------------------------
extern "C" void kernel_launch(void* const* d_in, const int* in_sizes, int n_in,
                              void* d_out, int out_size, void* d_ws, size_t ws_size,
                              hipStream_t stream) {
    const float* feats = (const float*)d_in[0];
    const float* pos   = (const float*)d_in[1];
    const int*   nidx  = (const int*)d_in[2];
    // d_in[3] (neighbor_mask) unused: mask recomputed exactly.
    const float* W1 = (const float*)d_in[4];
    const float* b1 = (const float*)d_in[5];
    const float* W2 = (const float*)d_in[6];
    const float* b2 = (const float*)d_in[7];
    const float* W3 = (const float*)d_in[8];
    const float* b3 = (const float*)d_in[9];
    const float* Wfc1 = (const float*)d_in[10];
    const float* bfc1 = (const float*)d_in[11];
    const float* Wfc2 = (const float*)d_in[12];
    const float* bfc2 = (const float*)d_in[13];
    const float* Wfc3 = (const float*)d_in[14];
    const float* bfc3 = (const float*)d_in[15];
    const float* Wout = (const float*)d_in[16];
    const float* bout = (const float*)d_in[17];

    char* ws = (char*)d_ws;
    uint2* contrib = (uint2*)(ws);                    // 20,578,304 B
    int*   starts  = (int*)  (ws + 20578304);         //    136,276 B
    float* cnt     = (float*)(ws + 20714624);         //     40,000 B
    float* x1      = (float*)(ws + 20754624);         //  2,560,000 B
    float* x2      = (float*)(ws + 23314624);         //  2,560,000 B
    float* x3      = (float*)(ws + 25874624);         //  1,280,000 B
    // geo (5.12 MB) dead after sort -> alias with partial region (10.24 MB)
    uint4* geo     = (uint4*)(ws + 27154624);
    float* partial = (float*)(ws + 27154624);

    hipMemsetAsync(cnt, 0, NPTS * sizeof(float), stream);
    geom_kernel<<<(NPTS * KNB) / 256, 256, 0, stream>>>(pos, nidx, geo, cnt);
    sort_kernel<<<NSGT, 256, 0, stream>>>(geo, contrib, starts);

    // conv1: CIN=4, COUT=64, KSPLIT=4 -> partial 10.24 MB, direct stores
    conv_kernel<4, 64, 4><<<dim3(NSGT, 4), 512, 0, stream>>>(
        feats, W1, contrib, starts, partial);
    combine_kernel<64, 4><<<(NPTS * 64 + 255) / 256, 256, 0, stream>>>(
        partial, cnt, b1, x1);

    // conv2: CIN=64, COUT=64, KSPLIT=4
    conv_kernel<64, 64, 4><<<dim3(NSGT, 4), 512, 0, stream>>>(
        x1, W2, contrib, starts, partial);
    combine_kernel<64, 4><<<(NPTS * 64 + 255) / 256, 256, 0, stream>>>(
        partial, cnt, b2, x2);

    // conv3: CIN=64, COUT=32, KSPLIT=8 -> partial 10.24 MB
    conv_kernel<64, 32, 8><<<dim3(NSGT, 8), 512, 0, stream>>>(
        x2, W3, contrib, starts, partial);
    combine_kernel<32, 8><<<(NPTS * 32 + 255) / 256, 256, 0, stream>>>(
        partial, cnt, b3, x3);

    fc_kernel<<<NPTS, 64, 0, stream>>>(x3, Wfc1, bfc1, Wfc2, bfc2,
                                       Wfc3, bfc3, Wout, bout, (float*)d_out);
}

// Round 9
// 2604.718 us; speedup vs baseline: 1.3536x; 1.3536x over previous
//
#include <hip/hip_runtime.h>
#include <math.h>

#define NPTS  10000
#define KNB   32
#define NCELL 216     // 6*6*6
#define NSGT  157     // ceil(NPTS/64) sort groups

// ---------------------------------------------------------------------------
// helpers
// ---------------------------------------------------------------------------
__device__ __forceinline__ float sgnf(float v) {
    return (v > 0.0f) ? 1.0f : ((v < 0.0f) ? -1.0f : 0.0f);
}

// Open3D ball->cube volume-preserving map, transcribed from the reference.
__device__ __forceinline__ void ball_to_cube(float x, float y, float z,
                                             float& X, float& Y, float& Z) {
    const float EPSF = 1e-12f;
    const float FOPI = (float)(4.0 / 3.14159265358979323846);
    float sq   = x * x + y * y + z * z;
    float norm = sqrtf(fmaxf(sq, EPSF));
    float rho2 = x * x + y * y;
    bool in_cone = (1.25f * z * z > rho2);
    float s1 = sqrtf(3.0f * norm / (norm + fabsf(z)));
    float s2 = norm / sqrtf(fmaxf(rho2, EPSF));
    float s  = in_cone ? s1 : s2;
    float xc = x * s;
    float yc = y * s;
    float zc = in_cone ? sgnf(z) * norm : 1.5f * z;
    if (sq < EPSF) { xc = 0.0f; yc = 0.0f; zc = 0.0f; }
    float sq_xy   = xc * xc + yc * yc;
    float norm_xy = sqrtf(fmaxf(sq_xy, EPSF));
    bool x_major = (fabsf(yc) <= fabsf(xc));
    float xd = (fabsf(xc) < EPSF) ? 1.0f : xc;
    float yd = (fabsf(yc) < EPSF) ? 1.0f : yc;
    float tx = sgnf(xc) * norm_xy;
    float ty = sgnf(yc) * norm_xy;
    float xq = x_major ? tx : ty * FOPI * atanf(xc / yd);
    float yq = x_major ? tx * FOPI * atanf(yc / xd) : ty;
    if (sq_xy < EPSF) { xq = 0.0f; yq = 0.0f; }
    X = xq; Y = yq; Z = zc;
}

// ---------------------------------------------------------------------------
// Kernel 1: per-(point,neighbor) geometry record + neighbor counts.
// Record (uint4): x,y,z = trilinear fracs (fp32 bits); w = packed:
//   [7:0]=c000 cell, [8]=dx?, [9]=dy?, [10]=dz?, [11]=valid, [25:12]=nidx
// ---------------------------------------------------------------------------
__global__ __launch_bounds__(256) void geom_kernel(
    const float* __restrict__ pos, const int* __restrict__ nidx,
    uint4* __restrict__ geo, float* __restrict__ cnt) {
    int t = blockIdx.x * 256 + threadIdx.x;
    if (t >= NPTS * KNB) return;
    int j = t >> 5;
    int k = t & 31;
    int nid = nidx[t];
    float px = pos[j * 3], py = pos[j * 3 + 1], pz = pos[j * 3 + 2];
    float qx = pos[nid * 3], qy = pos[nid * 3 + 1], qz = pos[nid * 3 + 2];
    // exact fp32 (no FMA contraction) to reproduce numpy's mask bit-for-bit
    float dx = __fsub_rn(px, qx), dy = __fsub_rn(py, qy), dz = __fsub_rn(pz, qz);
    float d2 = __fadd_rn(__fadd_rn(__fmul_rn(dx, dx), __fmul_rn(dy, dy)),
                         __fmul_rn(dz, dz));
    bool valid = (d2 <= 2.25f);
    if (valid && nid == 0) {
        for (int kk = 0; kk < k; ++kk) {
            if (nidx[j * KNB + kk] == 0) { valid = false; break; }
        }
    }
    uint4 g = make_uint4(0u, 0u, 0u, 0u);
    if (valid) {
        const float C = (float)(2.0 / 3.0);   // 2/EXTENT
        float ux = (qx - px) * C, uy = (qy - py) * C, uz = (qz - pz) * C;
        float X, Y, Z;
        ball_to_cube(ux, uy, uz, X, Y, Z);
        float cs[3] = { (X + 1.0f) * 2.5f, (Y + 1.0f) * 2.5f, (Z + 1.0f) * 2.5f };
        int i0[3], i1[3];
        float fr[3];
        #pragma unroll
        for (int d = 0; d < 3; ++d) {
            float f0 = floorf(cs[d]);
            fr[d] = cs[d] - f0;               // frac from UNCLIPPED floor (ref)
            int a = (int)f0;
            a = min(max(a, 0), 5);
            i0[d] = a;
            i1[d] = min(a + 1, 5);
        }
        int c000 = (i0[0] * 6 + i0[1]) * 6 + i0[2];
        unsigned bits = (unsigned)c000
                      | ((unsigned)(i1[0] - i0[0]) << 8)
                      | ((unsigned)(i1[1] - i0[1]) << 9)
                      | ((unsigned)(i1[2] - i0[2]) << 10)
                      | (1u << 11)
                      | ((unsigned)nid << 12);
        g.x = __float_as_uint(fr[0]);
        g.y = __float_as_uint(fr[1]);
        g.z = __float_as_uint(fr[2]);
        g.w = bits;
        atomicAdd(&cnt[j], 1.0f);
    }
    geo[t] = g;
}

// ---------------------------------------------------------------------------
// Kernel 2: counting sort of corner contributions by CELL per 64-pt sort
// group. Payload packs nid | ptl<<14 | cell<<20. starts[sg][217] = per-cell
// prefix. Built once, consumed by all 3 conv layers.
// ---------------------------------------------------------------------------
__global__ __launch_bounds__(256) void sort_kernel(
    const uint4* __restrict__ geo, uint2* __restrict__ contribs,
    int* __restrict__ starts) {
    __shared__ int hist[NCELL];
    __shared__ int pref[NCELL + 1];
    const int sg = blockIdx.x, tid = threadIdx.x;
    if (tid < NCELL) hist[tid] = 0;
    __syncthreads();
    const int npts = min(64, NPTS - sg * 64);
    const int nrec = npts * KNB;
    const uint4* gb = geo + (size_t)sg * 64 * KNB;
    for (int r = tid; r < nrec; r += 256) {
        uint4 g = gb[r];
        if (g.w & 2048u) {
            int c000 = g.w & 255u;
            int dxo = (g.w & 256u)  ? 36 : 0;
            int dyo = (g.w & 512u)  ? 6  : 0;
            int dzo = (g.w & 1024u) ? 1  : 0;
            #pragma unroll
            for (int c = 0; c < 8; ++c) {
                int cell = c000 + ((c & 4) ? dxo : 0) + ((c & 2) ? dyo : 0)
                                + ((c & 1) ? dzo : 0);
                atomicAdd(&hist[cell], 1);
            }
        }
    }
    __syncthreads();
    if (tid == 0) {
        int run = 0;
        for (int m = 0; m < NCELL; ++m) { pref[m] = run; run += hist[m]; }
        pref[NCELL] = run;
    }
    __syncthreads();
    for (int i = tid; i < NCELL + 1; i += 256)
        starts[sg * (NCELL + 1) + i] = pref[i];
    if (tid < NCELL) hist[tid] = pref[tid];   // cursors
    __syncthreads();
    uint2* cb = contribs + (size_t)sg * 16384;
    for (int r = tid; r < nrec; r += 256) {
        uint4 g = gb[r];
        if (g.w & 2048u) {
            int ptl = r >> 5;
            float fx = __uint_as_float(g.x);
            float fy = __uint_as_float(g.y);
            float fz = __uint_as_float(g.z);
            int c000 = g.w & 255u;
            int dxo = (g.w & 256u)  ? 36 : 0;
            int dyo = (g.w & 512u)  ? 6  : 0;
            int dzo = (g.w & 1024u) ? 1  : 0;
            int nid = (g.w >> 12) & 16383u;
            #pragma unroll
            for (int c = 0; c < 8; ++c) {
                float wgt = ((c & 4) ? fx : 1.f - fx)
                          * ((c & 2) ? fy : 1.f - fy)
                          * ((c & 1) ? fz : 1.f - fz);
                int cell = c000 + ((c & 4) ? dxo : 0) + ((c & 2) ? dyo : 0)
                                + ((c & 1) ? dzo : 0);
                int p = atomicAdd(&hist[cell], 1);
                cb[p] = make_uint2(__float_as_uint(wgt),
                                   (unsigned)nid | ((unsigned)ptl << 14)
                                                 | ((unsigned)cell << 20));
            }
        }
    }
}

// ---------------------------------------------------------------------------
// Kernel 3: record-streaming gather conv, readlane-broadcast inner loop.
//   Block = (sort group, cell segment). 8 waves; each wave takes a
//   CONTIGUOUS 1/8 slice of the block's record range (record-count
//   balanced). No barriers in the main loop.
//   lane = co (COUT=32: lanes>=32 masked at the atomic); W block for the
//   current cell resident in Wreg[CIN] VGPRs, reloaded on cell change
//   (wave-uniform scalar branch, ~once per ~70 records).
//   Per record: 1 coalesced feats-row load (lane = ci) pipelined 3 deep;
//   the ci-broadcast is CIN x v_readlane -> SGPR feeding v_fmac directly —
//   NO LDS round-trip, no bpermute, no barriers. Record fields decoded via
//   readlane from a register-resident 64-record window (prefetched).
//   4 partial accumulators; 1 conflict-free LDS atomic per record.
// ---------------------------------------------------------------------------
template<int CIN, int COUT, int KSPLIT>
__global__ __launch_bounds__(512, 4) void conv_kernel(
    const float* __restrict__ feats, const float* __restrict__ W,
    const uint2* __restrict__ contribs, const int* __restrict__ starts,
    float* __restrict__ partial) {

    __shared__ float out_lds[64 * COUT];

    const int tid  = threadIdx.x;
    const int lane = tid & 63;
    const int wv   = tid >> 6;
    const int bx   = blockIdx.x;           // sort group
    const int ks   = blockIdx.y;
    const int co   = lane & (COUT - 1);
    const int fidx = (CIN < 64) ? (lane & (CIN - 1)) : lane;

    const uint2* cbs = contribs + (size_t)bx * 16384;
    const int*   st  = starts + bx * (NCELL + 1);

    const int cell0 = NCELL * ks / KSPLIT;
    const int cell1 = NCELL * (ks + 1) / KSPLIT;

    for (int i = tid; i < 64 * COUT; i += 512) out_lds[i] = 0.f;
    __syncthreads();

    const int R0 = st[cell0], R1 = st[cell1];
    const int total = R1 - R0;
    const int ws_ = R0 + (total * wv) / 8;
    const int we_ = R0 + (total * (wv + 1)) / 8;

    auto rlu = [&](unsigned v, int r) -> int {
        return __builtin_amdgcn_readlane((int)v, r);
    };
    auto ldf = [&](int y) -> float {
        return feats[(size_t)(y & 16383) * CIN + fidx];
    };

    float Wreg[CIN];
    int scell = -1;

    if (ws_ < we_) {
        uint2 vrec = cbs[min(ws_ + lane, 16383)];
        for (int wb = ws_; wb < we_; wb += 64) {
            const int n = min(64, we_ - wb);
            uint2 vnext = vrec;
            if (wb + 64 < we_) vnext = cbs[min(wb + 64 + lane, 16383)];
            // 3-deep f pipeline: A = record r, B = r+1, C = r+2
            int yA = rlu(vrec.y, 0);
            float fA = ldf(yA);
            int yB = yA; float fB = fA;
            if (n > 1) { yB = rlu(vrec.y, 1); fB = ldf(yB); }
            for (int r = 0; r < n; ++r) {
                int yC = yB; float fC = fB;
                if (r + 2 < n) { yC = rlu(vrec.y, r + 2); fC = ldf(yC); }
                const int cell = (int)((unsigned)yA >> 20);
                const int ptl  = (yA >> 14) & 63;
                if (cell != scell) {
                    scell = cell;
                    #pragma unroll
                    for (int ci = 0; ci < CIN; ++ci)
                        Wreg[ci] = W[((size_t)cell * CIN + ci) * COUT + co];
                }
                float d0 = 0.f, d1 = 0.f, d2 = 0.f, d3 = 0.f;
                if constexpr (CIN >= 4) {
                    #pragma unroll
                    for (int q = 0; q < CIN / 4; ++q) {
                        float a0 = __int_as_float(rlu(__float_as_uint(fA), 4 * q + 0));
                        float a1 = __int_as_float(rlu(__float_as_uint(fA), 4 * q + 1));
                        float a2 = __int_as_float(rlu(__float_as_uint(fA), 4 * q + 2));
                        float a3 = __int_as_float(rlu(__float_as_uint(fA), 4 * q + 3));
                        d0 = fmaf(a0, Wreg[4 * q + 0], d0);
                        d1 = fmaf(a1, Wreg[4 * q + 1], d1);
                        d2 = fmaf(a2, Wreg[4 * q + 2], d2);
                        d3 = fmaf(a3, Wreg[4 * q + 3], d3);
                    }
                }
                float w = __int_as_float(rlu(vrec.x, r));
                float val = w * ((d0 + d1) + (d2 + d3));
                if (COUT == 64 || lane < COUT)
                    atomicAdd(&out_lds[ptl * COUT + co], val);
                yA = yB; fA = fB; yB = yC; fB = fC;
            }
            vrec = vnext;
        }
    }

    __syncthreads();
    for (int i = tid; i < 64 * COUT; i += 512) {
        int ptl = i / COUT, c = i % COUT;
        int nn = bx * 64 + ptl;
        if (nn < NPTS)
            partial[((size_t)ks * NPTS + nn) * COUT + c] = out_lds[i];
    }
}

// ---------------------------------------------------------------------------
// Kernel 4: combine K-split partials, normalize by neighbor count, bias, relu.
// ---------------------------------------------------------------------------
template<int COUT, int KSPLIT>
__global__ __launch_bounds__(256) void combine_kernel(
    const float* __restrict__ partial, const float* __restrict__ cnt,
    const float* __restrict__ bias, float* __restrict__ out) {
    int idx = blockIdx.x * 256 + threadIdx.x;
    if (idx >= NPTS * COUT) return;
    int n = idx / COUT, co = idx % COUT;
    float s = 0.f;
    #pragma unroll
    for (int k2 = 0; k2 < KSPLIT; ++k2)
        s += partial[((size_t)k2 * NPTS + n) * COUT + co];
    float c = cnt[n];
    if (c > 0.f) s /= fmaxf(c, 1.f);
    out[idx] = fmaxf(s + bias[co], 0.f);
}

// ---------------------------------------------------------------------------
// Kernel 5: fused FC chain. One wave per point, __shfl broadcasts.
// ---------------------------------------------------------------------------
__global__ __launch_bounds__(64) void fc_kernel(
    const float* __restrict__ x,
    const float* __restrict__ W1, const float* __restrict__ b1,
    const float* __restrict__ W2, const float* __restrict__ b2,
    const float* __restrict__ W3, const float* __restrict__ b3,
    const float* __restrict__ W4, const float* __restrict__ b4,
    float* __restrict__ out) {
    int n = blockIdx.x;
    int lane = threadIdx.x;
    float xv = (lane < 32) ? x[(size_t)n * 32 + lane] : 0.0f;

    float t = b1[lane];
    for (int ci = 0; ci < 32; ++ci)
        t = fmaf(__shfl(xv, ci), W1[ci * 64 + lane], t);
    float h1 = fmaxf(t, 0.0f);

    t = b2[lane];
    for (int ci = 0; ci < 64; ++ci)
        t = fmaf(__shfl(h1, ci), W2[ci * 64 + lane], t);
    float h2 = fmaxf(t, 0.0f);

    int l32 = lane & 31;
    t = b3[l32];
    for (int ci = 0; ci < 64; ++ci)
        t = fmaf(__shfl(h2, ci), W3[ci * 32 + l32], t);
    float h3 = fmaxf(t, 0.0f);

    int ch = (lane < 3) ? lane : 0;
    float o = b4[ch];
    for (int ci = 0; ci < 32; ++ci)
        o = fmaf(__shfl(h3, ci), W4[ci * 3 + ch], o);
    if (lane < 3) out[(size_t)n * 3 + lane] = o;
}

// ---------------------------------------------------------------------------
// launch
// ---------------------------------------------------------------------------
extern "C" void kernel_launch(void* const* d_in, const int* in_sizes, int n_in,
                              void* d_out, int out_size, void* d_ws, size_t ws_size,
                              hipStream_t stream) {
    const float* feats = (const float*)d_in[0];
    const float* pos   = (const float*)d_in[1];
    const int*   nidx  = (const int*)d_in[2];
    // d_in[3] (neighbor_mask) unused: mask recomputed exactly.
    const float* W1 = (const float*)d_in[4];
    const float* b1 = (const float*)d_in[5];
    const float* W2 = (const float*)d_in[6];
    const float* b2 = (const float*)d_in[7];
    const float* W3 = (const float*)d_in[8];
    const float* b3 = (const float*)d_in[9];
    const float* Wfc1 = (const float*)d_in[10];
    const float* bfc1 = (const float*)d_in[11];
    const float* Wfc2 = (const float*)d_in[12];
    const float* bfc2 = (const float*)d_in[13];
    const float* Wfc3 = (const float*)d_in[14];
    const float* bfc3 = (const float*)d_in[15];
    const float* Wout = (const float*)d_in[16];
    const float* bout = (const float*)d_in[17];

    char* ws = (char*)d_ws;
    uint2* contrib = (uint2*)(ws);                    // 20,578,304 B
    int*   starts  = (int*)  (ws + 20578304);         //    136,276 B
    float* cnt     = (float*)(ws + 20714624);         //     40,000 B
    float* x1      = (float*)(ws + 20754624);         //  2,560,000 B
    float* x2      = (float*)(ws + 23314624);         //  2,560,000 B
    float* x3      = (float*)(ws + 25874624);         //  1,280,000 B
    // geo (5.12 MB) dead after sort -> alias with partial region (10.24 MB)
    uint4* geo     = (uint4*)(ws + 27154624);
    float* partial = (float*)(ws + 27154624);

    hipMemsetAsync(cnt, 0, NPTS * sizeof(float), stream);
    geom_kernel<<<(NPTS * KNB) / 256, 256, 0, stream>>>(pos, nidx, geo, cnt);
    sort_kernel<<<NSGT, 256, 0, stream>>>(geo, contrib, starts);

    // conv1: CIN=4, COUT=64, KSPLIT=4 -> partial 10.24 MB, direct stores
    conv_kernel<4, 64, 4><<<dim3(NSGT, 4), 512, 0, stream>>>(
        feats, W1, contrib, starts, partial);
    combine_kernel<64, 4><<<(NPTS * 64 + 255) / 256, 256, 0, stream>>>(
        partial, cnt, b1, x1);

    // conv2: CIN=64, COUT=64, KSPLIT=4
    conv_kernel<64, 64, 4><<<dim3(NSGT, 4), 512, 0, stream>>>(
        x1, W2, contrib, starts, partial);
    combine_kernel<64, 4><<<(NPTS * 64 + 255) / 256, 256, 0, stream>>>(
        partial, cnt, b2, x2);

    // conv3: CIN=64, COUT=32, KSPLIT=4 -> partial 5.12 MB
    conv_kernel<64, 32, 4><<<dim3(NSGT, 4), 512, 0, stream>>>(
        x2, W3, contrib, starts, partial);
    combine_kernel<32, 4><<<(NPTS * 32 + 255) / 256, 256, 0, stream>>>(
        partial, cnt, b3, x3);

    fc_kernel<<<NPTS, 64, 0, stream>>>(x3, Wfc1, bfc1, Wfc2, bfc2,
                                       Wfc3, bfc3, Wout, bout, (float*)d_out);
}